// Round 4
// baseline (27.021 us; speedup 1.0000x reference)
//
#include <hip/hip_runtime.h>

// GaussianEmbedding margin loss — SINGLE kernel node.
//
// Algebra: in kl_neg - kl_pos the -1 and -ln(s1) terms cancel; per element
// only a SIGNED (s1 + d^2)*rcp(s2) + ln(s2) survives (-1 pos, +1 neg).
//
// One wave per b (1024 waves = 256 blocks x 4 waves). Lanes 0-31 handle the
// pos row, lanes 32-63 the neg row; each lane owns 4 elems (float4 gathers).
// One 64-lane butterfly per w gives D_w = kl_neg - kl_pos directly.
//
// Final reduction WITHOUT a second kernel or counter memset: every wave
// atomicAdds a persistent counter in d_ws. Counter is NEVER reset; it
// advances by exactly 1024 per launch, so exactly one wave per launch sees
// old % 1024 == 1023 (true for ANY initial value, incl. 0xAA poison). That
// wave re-reads all 1024 partials in fixed order and writes the mean ->
// bitwise-deterministic output, no spin-waits, no dispatch-order assumption.

constexpr int E = 128;
constexpr int W = 5;
constexpr int NB = 1024;               // B
constexpr float MARGIN = 0.1f;
constexpr float LN2 = 0.69314718055994530942f;

__global__ __launch_bounds__(256) void gauss_emb_fused(
    const float* __restrict__ mu, const float* __restrict__ sigma,
    const int* __restrict__ target, const int* __restrict__ cpos,
    const int* __restrict__ cneg, float* __restrict__ partial,
    unsigned int* __restrict__ counter, float* __restrict__ out)
{
    const int wave = threadIdx.x >> 6;
    const int lane = threadIdx.x & 63;
    const int b    = blockIdx.x * 4 + wave;
    const int half = lane >> 5;            // 0 = pos row, 1 = neg row
    const int sub  = lane & 31;            // elem group: 4*sub .. 4*sub+3

    const int t = target[b];
    const float4 m1 = ((const float4*)(mu    + (size_t)t * E))[sub];
    const float4 s1 = ((const float4*)(sigma + (size_t)t * E))[sub];

    int idx[W];
#pragma unroll
    for (int w = 0; w < W; ++w) {
        const int ip = cpos[b * W + w];
        const int in = cneg[b * W + w];
        idx[w] = half ? in : ip;           // v_cndmask
    }

    // Issue all gathers before any compute.
    float4 m2[W], s2[W];
#pragma unroll
    for (int w = 0; w < W; ++w) {
        m2[w] = ((const float4*)(mu    + (size_t)idx[w] * E))[sub];
        s2[w] = ((const float4*)(sigma + (size_t)idx[w] * E))[sub];
    }

    const float sign = half ? 1.0f : -1.0f;

    float dW[W];
#pragma unroll
    for (int w = 0; w < W; ++w) {
        float acc = 0.f;
#pragma unroll
        for (int j = 0; j < 4; ++j) {
            const float m1j = ((const float*)&m1)[j];
            const float s1j = ((const float*)&s1)[j];
            const float m2j = ((const float*)&m2[w])[j];
            const float s2j = ((const float*)&s2[w])[j];
            const float d   = m2j - m1j;
            acc += (s1j + d * d) * __builtin_amdgcn_rcpf(s2j)
                 + LN2 * __log2f(s2j);
        }
        dW[w] = sign * acc;
    }

#pragma unroll
    for (int w = 0; w < W; ++w) {
#pragma unroll
        for (int off = 32; off >= 1; off >>= 1)
            dW[w] += __shfl_xor(dW[w], off, 64);
    }

    int last = 0;
    if (lane == 0) {
        float h = 0.f;
#pragma unroll
        for (int w = 0; w < W; ++w)
            h += fmaxf(0.f, MARGIN + 0.5f * dW[w]);
        partial[b] = h;
        __threadfence();                          // release partial[b]
        const unsigned int old = atomicAdd(counter, 1u);
        last = ((old & (NB - 1u)) == (NB - 1u));  // exactly one wave/launch
    }
    last = __shfl(last, 0, 64);

    if (last) {
        __threadfence();                          // acquire all partials
        const float4* p4 = (const float4*)partial;  // 256 float4
        float s = 0.f;
#pragma unroll
        for (int k = 0; k < 4; ++k) {
            const float4 v = p4[lane + 64 * k];
            s += v.x + v.y + v.z + v.w;
        }
#pragma unroll
        for (int off = 32; off >= 1; off >>= 1)
            s += __shfl_xor(s, off, 64);
        if (lane == 0) out[0] = s * (1.0f / (float)NB);
    }
}

extern "C" void kernel_launch(void* const* d_in, const int* in_sizes, int n_in,
                              void* d_out, int out_size, void* d_ws, size_t ws_size,
                              hipStream_t stream)
{
    const float* mu     = (const float*)d_in[0];
    const float* sigma  = (const float*)d_in[1];
    const int*   target = (const int*)d_in[2];
    const int*   cpos   = (const int*)d_in[3];
    const int*   cneg   = (const int*)d_in[4];
    float*        partial = (float*)d_ws;                       // 4 KiB
    unsigned int* counter = (unsigned int*)((char*)d_ws + 4096); // persistent

    gauss_emb_fused<<<NB / 4, 256, 0, stream>>>(mu, sigma, target, cpos, cneg,
                                                partial, counter, (float*)d_out);
}

// Round 5
// 11.381 us; speedup vs baseline: 2.3742x; 2.3742x over previous
//
#include <hip/hip_runtime.h>

// GaussianEmbedding margin loss, two-kernel structure.
// Measured: coop-launch single node = 43us, atomic-last-wave single node = 27us,
// two plain nodes = 11.4us -> in-kernel grid sync is never worth it here.
//
// Algebra: in kl_neg - kl_pos the -1 and -ln(s1) terms cancel; per element
// only a SIGNED (s1 + d^2)*rcp(s2) + ln(s2) survives (-1 pos, +1 neg).
//
// Kernel 1: 256 wg x 256 thr (4 waves/wg, fewer CP dispatches than 1024x64).
// One wave per b. Lanes 0-31 handle the pos row, lanes 32-63 the neg row;
// each lane owns 4 elems (float4 gathers -> 12 x 16B per wave, all issued
// before compute). One 64-lane butterfly per w gives D_w = kl_neg - kl_pos.
// Kernel 2: single wave, deterministic reduction of 1024 partials, /B.

constexpr int E = 128;
constexpr int W = 5;
constexpr int NB = 1024;               // B
constexpr float MARGIN = 0.1f;
constexpr float LN2 = 0.69314718055994530942f;

__global__ __launch_bounds__(256) void gauss_emb_kl(
    const float* __restrict__ mu, const float* __restrict__ sigma,
    const int* __restrict__ target, const int* __restrict__ cpos,
    const int* __restrict__ cneg, float* __restrict__ partial)
{
    const int wave = threadIdx.x >> 6;
    const int lane = threadIdx.x & 63;
    const int b    = blockIdx.x * 4 + wave;
    const int half = lane >> 5;            // 0 = pos row, 1 = neg row
    const int sub  = lane & 31;            // elem group: 4*sub .. 4*sub+3

    const int t = target[b];
    const float4 m1 = ((const float4*)(mu    + (size_t)t * E))[sub];
    const float4 s1 = ((const float4*)(sigma + (size_t)t * E))[sub];

    int idx[W];
#pragma unroll
    for (int w = 0; w < W; ++w) {
        const int ip = cpos[b * W + w];
        const int in = cneg[b * W + w];
        idx[w] = half ? in : ip;           // v_cndmask
    }

    // Issue all gathers before any compute.
    float4 m2[W], s2[W];
#pragma unroll
    for (int w = 0; w < W; ++w) {
        m2[w] = ((const float4*)(mu    + (size_t)idx[w] * E))[sub];
        s2[w] = ((const float4*)(sigma + (size_t)idx[w] * E))[sub];
    }

    const float sign = half ? 1.0f : -1.0f;

    float dW[W];
#pragma unroll
    for (int w = 0; w < W; ++w) {
        float acc = 0.f;
#pragma unroll
        for (int j = 0; j < 4; ++j) {
            const float m1j = ((const float*)&m1)[j];
            const float s1j = ((const float*)&s1)[j];
            const float m2j = ((const float*)&m2[w])[j];
            const float s2j = ((const float*)&s2[w])[j];
            const float d   = m2j - m1j;
            acc += (s1j + d * d) * __builtin_amdgcn_rcpf(s2j)
                 + LN2 * __log2f(s2j);
        }
        dW[w] = sign * acc;
    }

#pragma unroll
    for (int w = 0; w < W; ++w) {
#pragma unroll
        for (int off = 32; off >= 1; off >>= 1)
            dW[w] += __shfl_xor(dW[w], off, 64);
    }

    if (lane == 0) {
        float h = 0.f;
#pragma unroll
        for (int w = 0; w < W; ++w)
            h += fmaxf(0.f, MARGIN + 0.5f * dW[w]);
        partial[b] = h;
    }
}

__global__ __launch_bounds__(64) void gauss_emb_reduce(
    const float* __restrict__ partial, float* __restrict__ out)
{
    const int lane = threadIdx.x;
    const float4* p4 = (const float4*)partial;   // 256 float4
    float s = 0.f;
#pragma unroll
    for (int k = 0; k < 4; ++k) {
        const float4 v = p4[lane + 64 * k];
        s += v.x + v.y + v.z + v.w;
    }
#pragma unroll
    for (int off = 32; off >= 1; off >>= 1)
        s += __shfl_xor(s, off, 64);
    if (lane == 0) out[0] = s * (1.0f / (float)NB);
}

extern "C" void kernel_launch(void* const* d_in, const int* in_sizes, int n_in,
                              void* d_out, int out_size, void* d_ws, size_t ws_size,
                              hipStream_t stream)
{
    const float* mu     = (const float*)d_in[0];
    const float* sigma  = (const float*)d_in[1];
    const int*   target = (const int*)d_in[2];
    const int*   cpos   = (const int*)d_in[3];
    const int*   cneg   = (const int*)d_in[4];
    float* partial = (float*)d_ws;     // 4 KiB of scratch

    gauss_emb_kl<<<NB / 4, 256, 0, stream>>>(mu, sigma, target, cpos, cneg, partial);
    gauss_emb_reduce<<<1, 64, 0, stream>>>(partial, (float*)d_out);
}